// Round 6
// baseline (1293.538 us; speedup 1.0000x reference)
//
#include <hip/hip_runtime.h>
#include <stdint.h>

typedef unsigned short u16;
typedef __attribute__((ext_vector_type(8))) __bf16 bf16x8;
typedef __attribute__((ext_vector_type(4))) float f32x4;

#define AS1 __attribute__((address_space(1)))
#define AS3 __attribute__((address_space(3)))

// Problem constants (hardcoded: B=4, S=2048, T=256, H=2048, NH=16, HD=128)
constexpr int HB = 4;
constexpr int SS = 2048;
constexpr int TT = 256;
constexpr int HH = 2048;
constexpr int NHEAD = 16;
constexpr int HD = 128;

__device__ __forceinline__ u16 f2b(float f) {
  union { float f; uint32_t u; } c; c.f = f;
  return (u16)((c.u + 0x7FFFu + ((c.u >> 16) & 1u)) >> 16);
}

__device__ __forceinline__ float b2f(uint32_t lo16) {
  union { uint32_t u; float f; } c; c.u = lo16 << 16;
  return c.f;
}

// ---------------- all f32 -> bf16 casts in ONE launch ----------------
// regions (in float4-quads/256 blocks): hs 16384, at 2048, Wq/Wk/Wv/Wo 4096 each
__global__ __launch_bounds__(256)
void cast_all(const float* __restrict__ hs, const float* __restrict__ at,
              const float* __restrict__ wq, const float* __restrict__ wk,
              const float* __restrict__ wv, const float* __restrict__ wo,
              u16* __restrict__ o_hs, u16* __restrict__ o_at,
              u16* __restrict__ o_wq, u16* __restrict__ o_wk,
              u16* __restrict__ o_wv, u16* __restrict__ o_wo) {
  const int b = blockIdx.x;
  const float* src; u16* dst; int base;
  if (b < 16384)      { src = hs; dst = o_hs; base = 0; }
  else if (b < 18432) { src = at; dst = o_at; base = 16384; }
  else if (b < 22528) { src = wq; dst = o_wq; base = 18432; }
  else if (b < 26624) { src = wk; dst = o_wk; base = 22528; }
  else if (b < 30720) { src = wv; dst = o_wv; base = 26624; }
  else                { src = wo; dst = o_wo; base = 30720; }
  const size_t i = (size_t)(b - base) * 256 + threadIdx.x;
  const float4 v = *(const float4*)(src + i * 4);
  uint2 pk;
  pk.x = (uint32_t)f2b(v.x) | ((uint32_t)f2b(v.y) << 16);
  pk.y = (uint32_t)f2b(v.z) | ((uint32_t)f2b(v.w) << 16);
  *(uint2*)(dst + i * 4) = pk;
}

// ============ big GEMM (M multiple of 256, N=K=2048) =========================
// BM=256, BN=256, BK=32 slices. 8 waves (2m x 4n), per-wave 128x64 (8x4 frags).
// v2: TWO LDS buffers (64 KB) -> 2 blocks/CU co-resident; cross-block overlap
// fills the barrier/vmcnt bubbles that capped 1-block/CU at 46% MfmaUtil.
// Stage distance 2; slice t+2 staged into bb only after the mid-slice
// lgkmcnt(0)+barrier (all reads of bb provably drained). One barrier/slice;
// fragment reads pipelined one phase ahead as before.
// MODE 0: bf16 out. MODE 2: f32 out * clip(rs). MODE 3: bf16 out * clip(rs).
template<int MODE>
__global__ __launch_bounds__(512, 4)
void gemm8(const u16* __restrict__ A, const u16* __restrict__ Bw,
           const float* __restrict__ bias, const float* __restrict__ rsp,
           void* __restrict__ outp) {
  constexpr int KD = 2048, NT = 64;          // K slices of 32
  constexpr int BUF = 16384;                 // u16 per buffer (A 8192 + B 8192)
  __shared__ u16 lds[2 * BUF];               // 64 KB -> 2 blocks/CU
  const int tid = threadIdx.x;
  const int wv = tid >> 6, ln = tid & 63;
  const int lq = ln >> 4, lr = ln & 15;
  const int wm = wv >> 2, wn = wv & 3;

  // XCD-bijective block swizzle (nwg = 256, %8 == 0); n fastest within XCD
  const int linb = blockIdx.y * 8 + blockIdx.x;
  const int ns = (linb & 7) * 32 + (linb >> 3);
  const int m0 = (ns >> 3) * 256;
  const int n0 = (ns & 7) * 256;

  // stage source offsets (inverse-swizzled)
  int gOff[2];
#pragma unroll
  for (int c = 0; c < 2; ++c) {
    const int g = c * 512 + tid, sr = g >> 3, s = g & 7, l = s ^ (sr & 7);
    gOff[c] = (2 * sr + (l >> 2)) * KD + (l & 3) * 8;
  }
  const u16* Abase = A + (size_t)m0 * KD;
  const u16* Bbase = Bw + (size_t)n0 * KD;

  // swizzled read offsets (u16), loop-invariant
  int aoff[8], boff[4];
#pragma unroll
  for (int m = 0; m < 8; ++m) {
    const int R = wm * 128 + m * 16 + lr, sr = R >> 1;
    aoff[m] = sr * 64 + ((((R & 1) << 2) + lq) ^ (sr & 7)) * 8;
  }
#pragma unroll
  for (int j = 0; j < 4; ++j) {
    const int R = wn * 64 + j * 16 + lr, sr = R >> 1;
    boff[j] = 8192 + sr * 64 + ((((R & 1) << 2) + lq) ^ (sr & 7)) * 8;
  }

#define STAGE_A(c, k0, buf)                                                      \
  __builtin_amdgcn_global_load_lds((AS1 const void*)(Abase + (k0) + gOff[c]),    \
      (AS3 void*)(lds + (buf) * BUF + ((c) * 512 + wv * 64) * 8), 16, 0, 0)
#define STAGE_B(c, k0, buf)                                                      \
  __builtin_amdgcn_global_load_lds((AS1 const void*)(Bbase + (k0) + gOff[c]),    \
      (AS3 void*)(lds + (buf) * BUF + 8192 + ((c) * 512 + wv * 64) * 8), 16, 0, 0)

  f32x4 acc[8][4];
#pragma unroll
  for (int i = 0; i < 8; ++i)
#pragma unroll
    for (int j = 0; j < 4; ++j) acc[i][j] = (f32x4){0.f, 0.f, 0.f, 0.f};

  // prologue: slice 0 -> buf0, slice 1 -> buf1; wait slice 0 only
  STAGE_A(0, 0, 0);  STAGE_A(1, 0, 0);  STAGE_B(0, 0, 0);  STAGE_B(1, 0, 0);
  STAGE_A(0, 32, 1); STAGE_A(1, 32, 1); STAGE_B(0, 32, 1); STAGE_B(1, 32, 1);
  asm volatile("s_waitcnt vmcnt(4)" ::: "memory");
  __builtin_amdgcn_s_barrier();
  __builtin_amdgcn_sched_barrier(0);

  // preload slice-0 fragments (P0: B all 4, A m0-3)
  bf16x8 af[4], bf[4], afn[4];
#pragma unroll
  for (int j = 0; j < 4; ++j) bf[j] = *(const bf16x8*)(lds + boff[j]);
#pragma unroll
  for (int m = 0; m < 4; ++m) af[m] = *(const bf16x8*)(lds + aoff[m]);
  __builtin_amdgcn_sched_barrier(0);

  for (int t = 0; t < NT; ++t) {
    const u16* bb = lds + (t & 1) * BUF;
    const u16* bn = lds + ((t + 1) & 1) * BUF;
    const int k2 = (t + 2) * 32;
    const bool doStage = (t + 2) < NT;

    // P1 reads of current slice (A m4-7) -> drain under MFMA set0
#pragma unroll
    for (int m = 0; m < 4; ++m) afn[m] = *(const bf16x8*)(bb + aoff[4 + m]);
    asm volatile("s_waitcnt lgkmcnt(4)" ::: "memory");  // af,bf ready; afn in flight
    __builtin_amdgcn_sched_barrier(0);
    __builtin_amdgcn_s_setprio(1);
#pragma unroll
    for (int m = 0; m < 4; ++m)
#pragma unroll
      for (int j = 0; j < 4; ++j)
        acc[m][j] = __builtin_amdgcn_mfma_f32_16x16x32_bf16(af[m], bf[j], acc[m][j], 0, 0, 0);
    __builtin_amdgcn_s_setprio(0);
    asm volatile("s_waitcnt lgkmcnt(0)" ::: "memory");  // afn done; bb reads drained
    __builtin_amdgcn_s_barrier();                        // single barrier per slice
    __builtin_amdgcn_sched_barrier(0);
    // safe now: every wave's reads of bb completed -> restage bb with slice t+2
    if (doStage) {
      STAGE_A(0, k2, t & 1); STAGE_A(1, k2, t & 1);
      STAGE_B(0, k2, t & 1); STAGE_B(1, k2, t & 1);
      asm volatile("s_waitcnt vmcnt(4)" ::: "memory");   // slice t+1 landed
    } else {
      asm volatile("s_waitcnt vmcnt(0)" ::: "memory");
    }
    // next-slice P0 A reads -> drain under MFMA set1
    if (t + 1 < NT) {
#pragma unroll
      for (int m = 0; m < 4; ++m) af[m] = *(const bf16x8*)(bn + aoff[m]);
    }
    __builtin_amdgcn_s_setprio(1);
#pragma unroll
    for (int m = 0; m < 4; ++m)
#pragma unroll
      for (int j = 0; j < 4; ++j)
        acc[4 + m][j] = __builtin_amdgcn_mfma_f32_16x16x32_bf16(afn[m], bf[j], acc[4 + m][j], 0, 0, 0);
    __builtin_amdgcn_s_setprio(0);
    // next-slice B reads -> drain under next slice head; must precede next afn
    if (t + 1 < NT) {
#pragma unroll
      for (int j = 0; j < 4; ++j) bf[j] = *(const bf16x8*)(bn + boff[j]);
    }
    __builtin_amdgcn_sched_barrier(0);
  }
#undef STAGE_A
#undef STAGE_B

  float bj[4];
#pragma unroll
  for (int j = 0; j < 4; ++j) bj[j] = bias[n0 + wn * 64 + j * 16 + lr];
  float rsv = 0.f;
  if constexpr (MODE == 2 || MODE == 3) rsv = fminf(fmaxf(rsp[0], 0.0f), 0.3f);

#pragma unroll
  for (int i = 0; i < 8; ++i)
#pragma unroll
    for (int j = 0; j < 4; ++j)
#pragma unroll
      for (int r = 0; r < 4; ++r) {
        const int row = m0 + wm * 128 + i * 16 + lq * 4 + r;  // C/D: row=(lane>>4)*4+reg
        const int col = n0 + wn * 64 + j * 16 + lr;           //      col=lane&15
        const float v = acc[i][j][r] + bj[j];
        if constexpr (MODE == 0) {
          ((u16*)outp)[(size_t)row * 2048 + col] = f2b(v);
        } else if constexpr (MODE == 2) {
          ((float*)outp)[(size_t)row * 2048 + col] = v * rsv;
        } else {
          ((u16*)outp)[(size_t)row * 2048 + col] = f2b(v * rsv);
        }
      }
}

// -------- K+V projection in one launch (M=1024 each) --------
// blockIdx.z==0: K row-major out; z==1: V transposed out (Vt layout).
__global__ __launch_bounds__(256, 2)
void gemm_kv(const u16* __restrict__ A, const u16* __restrict__ Wk,
             const u16* __restrict__ Wv, const float* __restrict__ bkp,
             const float* __restrict__ bvp, u16* __restrict__ Ko,
             u16* __restrict__ Vto) {
  constexpr int KD = 2048, NT = 64;
  constexpr int BUFE = 8192;                 // u16 per slice buffer (A 4096 + B 4096)
  __shared__ u16 lds[4 * BUFE];              // 64 KB
  const bool isV = blockIdx.z != 0;
  const u16* Bw = isV ? Wv : Wk;
  const float* bias = isV ? bvp : bkp;
  const int tid = threadIdx.x;
  const int wave = tid >> 6, lane = tid & 63;
  const int lq = lane >> 4, lr = lane & 15;
  const int wr = wave >> 1, wc = wave & 1;
  const int m0 = blockIdx.y * 128, n0 = blockIdx.x * 128;

  // stage source offsets (inverse-swizzled); g in [0,512) chunks per region
  int gOff[2];
#pragma unroll
  for (int c = 0; c < 2; ++c) {
    const int g = c * 256 + tid, sr = g >> 3, s = g & 7, l = s ^ (sr & 7);
    gOff[c] = (2 * sr + (l >> 2)) * KD + (l & 3) * 8;
  }
  const u16* Abase = A + (size_t)m0 * KD;
  const u16* Bbase = Bw + (size_t)n0 * KD;

  // swizzled read offsets (u16), loop-invariant; 2 lanes/slot -> conflict-free
  int aoff[4], boff[4];
#pragma unroll
  for (int i = 0; i < 4; ++i) {
    const int R = wr * 64 + i * 16 + lr, sr = R >> 1;
    aoff[i] = sr * 64 + ((((R & 1) << 2) + lq) ^ (sr & 7)) * 8;
  }
#pragma unroll
  for (int j = 0; j < 4; ++j) {
    const int R = wc * 64 + j * 16 + lr, sr = R >> 1;
    boff[j] = 4096 + sr * 64 + ((((R & 1) << 2) + lq) ^ (sr & 7)) * 8;
  }

#define KV_STAGE(t3, buf)                                                         \
  {                                                                               \
    _Pragma("unroll")                                                             \
    for (int c_ = 0; c_ < 2; ++c_) {                                              \
      __builtin_amdgcn_global_load_lds(                                           \
          (AS1 const void*)(Abase + (t3) * 32 + gOff[c_]),                        \
          (AS3 void*)(lds + (buf) * BUFE + (c_ * 256 + wave * 64) * 8), 16, 0, 0);\
      __builtin_amdgcn_global_load_lds(                                           \
          (AS1 const void*)(Bbase + (t3) * 32 + gOff[c_]),                        \
          (AS3 void*)(lds + (buf) * BUFE + 4096 + (c_ * 256 + wave * 64) * 8),    \
          16, 0, 0);                                                              \
    }                                                                             \
  }

  f32x4 acc[4][4];
#pragma unroll
  for (int i = 0; i < 4; ++i)
#pragma unroll
    for (int j = 0; j < 4; ++j) acc[i][j] = (f32x4){0.f, 0.f, 0.f, 0.f};

  // prologue: slices 0,1,2 (4 loads each); wait slice 0 only
  KV_STAGE(0, 0); KV_STAGE(1, 1); KV_STAGE(2, 2);
  asm volatile("s_waitcnt vmcnt(8)" ::: "memory");
  __builtin_amdgcn_s_barrier();
  __builtin_amdgcn_sched_barrier(0);

  bf16x8 af[4], bfr[4];
#pragma unroll
  for (int i = 0; i < 4; ++i) af[i] = *(const bf16x8*)(lds + aoff[i]);
#pragma unroll
  for (int j = 0; j < 4; ++j) bfr[j] = *(const bf16x8*)(lds + boff[j]);
  __builtin_amdgcn_sched_barrier(0);

  for (int t = 0; t < NT; ++t) {
    if (t + 3 < NT) KV_STAGE(t + 3, (t + 3) & 3);
    asm volatile("s_waitcnt lgkmcnt(0)" ::: "memory");  // frags(t) ready (pre-barrier)
    __builtin_amdgcn_sched_barrier(0);
    __builtin_amdgcn_s_setprio(1);
#pragma unroll
    for (int i = 0; i < 4; ++i)
#pragma unroll
      for (int j = 0; j < 4; ++j)
        acc[i][j] = __builtin_amdgcn_mfma_f32_16x16x32_bf16(af[i], bfr[j], acc[i][j], 0, 0, 0);
    __builtin_amdgcn_s_setprio(0);
    if (t < NT - 3)       asm volatile("s_waitcnt vmcnt(8)" ::: "memory");
    else if (t == NT - 3) asm volatile("s_waitcnt vmcnt(4)" ::: "memory");
    else                  asm volatile("s_waitcnt vmcnt(0)" ::: "memory");
    __builtin_amdgcn_s_barrier();                       // single barrier per slice
    __builtin_amdgcn_sched_barrier(0);
    if (t + 1 < NT) {
      const u16* bn = lds + ((t + 1) & 3) * BUFE;
#pragma unroll
      for (int i = 0; i < 4; ++i) af[i] = *(const bf16x8*)(bn + aoff[i]);
#pragma unroll
      for (int j = 0; j < 4; ++j) bfr[j] = *(const bf16x8*)(bn + boff[j]);
    }
    __builtin_amdgcn_sched_barrier(0);
  }
#undef KV_STAGE

  float bj[4];
#pragma unroll
  for (int j = 0; j < 4; ++j) bj[j] = bias[n0 + wc * 64 + j * 16 + lr];

#pragma unroll
  for (int i = 0; i < 4; ++i)
#pragma unroll
    for (int j = 0; j < 4; ++j)
#pragma unroll
      for (int r = 0; r < 4; ++r) {
        const int row = m0 + wr * 64 + i * 16 + lq * 4 + r;
        const int col = n0 + wc * 64 + j * 16 + lr;
        const float v = acc[i][j][r] + bj[j];
        if (!isV) {
          Ko[(size_t)row * 2048 + col] = f2b(v);
        } else {
          Vto[(size_t)(row >> 8) * (2048 * 256) + (size_t)col * 256 + (row & 255)] = f2b(v);
        }
      }
}

// ---------------- fused cross-attention, v6: chunked + max-free softmax -----
// Proven v3 structure (grid (S/128, NH, B), 512 threads, K/V double-buffered
// LDS, counted vmcnt, per-chunk sc[4] only -> no spill) + max-free softmax:
// scores pre-clipped to [-50,50] => exp/sum f32-safe without max subtraction,
// p/sum == softmax exactly. Sum is a local accumulator reduced once at end.
__global__ __launch_bounds__(512, 4)
void attn_kernel(const u16* __restrict__ Q, const u16* __restrict__ Kb,
                 const u16* __restrict__ Vt, const int* __restrict__ mask,
                 u16* __restrict__ ctx) {
  __shared__ u16 sK[2][64 * 128];   // 2x16 KB, swz slot^(row&15)
  __shared__ u16 sVt[2][128 * 64];  // 2x16 KB, swz slot^(row&7)
  __shared__ u16 sP[8 * 16 * 64];   // 16 KB per-wave P quarter, XOR swz

  const int tid = threadIdx.x;
  const int wv = tid >> 6, ln = tid & 63;
  const int lq = ln >> 4, lr = ln & 15;
  const int h = blockIdx.y, b = blockIdx.z;
  const int s0blk = blockIdx.x * 128;
  u16* sPw = sP + wv * (16 * 64);

  // mask bits for lane lr: bit g = attend(t = g*16 + lr), g = c*4 + tt
  uint32_t mbits = 0;
#pragma unroll
  for (int g = 0; g < 16; ++g)
    mbits |= (mask[b * TT + g * 16 + lr] != 0 ? 1u : 0u) << g;

  // ---- Q fragments direct from global (loop-invariant) ----
  bf16x8 qf[4];
  {
    const u16* qp = Q + ((size_t)b * SS + s0blk + wv * 16 + lr) * HH + (size_t)h * HD + lq * 8;
#pragma unroll
    for (int kd = 0; kd < 4; ++kd) qf[kd] = *(const bf16x8*)(qp + kd * 32);
  }

#define STAGE_KV(c)                                                                      \
  {                                                                                      \
    const int buf_ = (c) & 1;                                                            \
    _Pragma("unroll")                                                                    \
    for (int it = 0; it < 2; ++it) {                                                     \
      const int ub = it * 512 + wv * 64;                                                 \
      const int u = ub + ln;                                                             \
      const int row = u >> 4, slot = u & 15, src = slot ^ (row & 15);                    \
      const u16* g = Kb + ((size_t)b * TT + (c) * 64 + row) * HH + h * HD + src * 8;     \
      __builtin_amdgcn_global_load_lds((AS1 const void*)g,                               \
          (AS3 void*)(sK[buf_] + (size_t)ub * 8), 16, 0, 0);                             \
    }                                                                                    \
    _Pragma("unroll")                                                                    \
    for (int it = 0; it < 2; ++it) {                                                     \
      const int ub = it * 512 + wv * 64;                                                 \
      const int u = ub + ln;                                                             \
      const int row = u >> 3, slot = u & 7, src = slot ^ (row & 7);                      \
      const u16* g = Vt + ((size_t)b * HH + h * HD + row) * TT + (c) * 64 + src * 8;     \
      __builtin_amdgcn_global_load_lds((AS1 const void*)g,                               \
          (AS3 void*)(sVt[buf_] + (size_t)ub * 8), 16, 0, 0);                            \
    }                                                                                    \
  }
  STAGE_KV(0);
  STAGE_KV(1);

  const float scale = 0.08838834764831845f;  // 1/sqrt(128)
  float ls[4] = {0.f, 0.f, 0.f, 0.f};       // per-lane partial softmax denom
  f32x4 o[8];  // ctx^T fragments: row d = lq*4+r within d0-tile, col q = lr
#pragma unroll
  for (int d0 = 0; d0 < 8; ++d0) o[d0] = (f32x4){0.f, 0.f, 0.f, 0.f};

  const int qrow = wv * 16 + lr;
  const int shsrc = ((lr >> 2) << 4) + lr;  // lane with lq = lr>>2 for q=lr state

  for (int c = 0; c < 4; ++c) {
    const int buf = c & 1;
    // chunk c landed when <= 4 loads (chunk c+1) outstanding
    if (c < 3) asm volatile("s_waitcnt vmcnt(4)" ::: "memory");
    else       asm volatile("s_waitcnt vmcnt(0)" ::: "memory");
    __syncthreads();

    // ---- QK^T: 4 t-tiles x K=128 (Q frags resident in registers) ----
    f32x4 sc[4];
#pragma unroll
    for (int tt = 0; tt < 4; ++tt) {
      f32x4 a = (f32x4){0.f, 0.f, 0.f, 0.f};
#pragma unroll
      for (int kd = 0; kd < 4; ++kd) {
        bf16x8 kf = *(const bf16x8*)(sK[buf] + (size_t)(tt * 16 + lr) * 128 + (size_t)((kd * 4 + lq) ^ lr) * 8);
        a = __builtin_amdgcn_mfma_f32_16x16x32_bf16(qf[kd], kf, a, 0, 0, 0);
      }
      sc[tt] = a;
    }

    // ---- scale/clip/mask -> exp (max-free) -> local sum accumulate ----
#pragma unroll
    for (int tt = 0; tt < 4; ++tt) {
      const bool on = (mbits >> (c * 4 + tt)) & 1;
#pragma unroll
      for (int r = 0; r < 4; ++r) {
        float v = sc[tt][r] * scale;
        v = fminf(fmaxf(v, -50.f), 50.f);
        v = on ? v : -50.f;
        const float p = __expf(v);
        sc[tt][r] = p;
        ls[r] += p;
      }
    }

    // ---- P (C-layout) -> per-wave LDS (XOR swz, 16B slots) -> fragments ----
#pragma unroll
    for (int tt = 0; tt < 4; ++tt)
#pragma unroll
      for (int r = 0; r < 4; ++r) {
        const int q = lq * 4 + r;
        const int slot = (tt * 2 + (lr >> 3)) ^ ((q >> 1) & 7);
        sPw[(size_t)q * 64 + slot * 8 + (lr & 7)] = f2b(sc[tt][r]);
      }

    bf16x8 pf[2];
#pragma unroll
    for (int kt = 0; kt < 2; ++kt) {
      const int slot = (kt * 4 + lq) ^ ((lr >> 1) & 7);
      pf[kt] = *(const bf16x8*)(sPw + (size_t)lr * 64 + slot * 8);
    }

    // ---- PV transposed: o^T[d][q] += Vt_A . P^T_B ----
#pragma unroll
    for (int d0 = 0; d0 < 8; ++d0)
#pragma unroll
      for (int kt = 0; kt < 2; ++kt) {
        bf16x8 vf = *(const bf16x8*)(sVt[buf] + (size_t)(d0 * 16 + lr) * 64 + (size_t)((kt * 4 + lq) ^ (lr & 7)) * 8);
        o[d0] = __builtin_amdgcn_mfma_f32_16x16x32_bf16(vf, pf[kt], o[d0], 0, 0, 0);
      }
    if (c < 2) {
      __syncthreads();  // all waves done with buf before restaging it
      STAGE_KV(c + 2);
    }
  }
#undef STAGE_KV

  // ---- single sum reduce across lr, then 1/l redistributed to q=lr ----
#pragma unroll
  for (int d = 1; d < 16; d <<= 1)
#pragma unroll
    for (int r = 0; r < 4; ++r) ls[r] += __shfl_xor(ls[r], d);

  const float i0 = __shfl(1.0f / ls[0], shsrc), i1 = __shfl(1.0f / ls[1], shsrc);
  const float i2 = __shfl(1.0f / ls[2], shsrc), i3 = __shfl(1.0f / ls[3], shsrc);
  const int rsel = lr & 3;
  const float iq = rsel == 0 ? i0 : rsel == 1 ? i1 : rsel == 2 ? i2 : i3;

  // ctx[q][d]: lane holds q = s0blk + wv*16 + lr, d = d0*16 + lq*4 + r
  const size_t cbase = ((size_t)b * SS + s0blk + wv * 16 + lr) * HH + (size_t)h * HD;
#pragma unroll
  for (int d0 = 0; d0 < 8; ++d0) {
    uint2 w;
    w.x = (uint32_t)f2b(o[d0][0] * iq) | ((uint32_t)f2b(o[d0][1] * iq) << 16);
    w.y = (uint32_t)f2b(o[d0][2] * iq) | ((uint32_t)f2b(o[d0][3] * iq) << 16);
    *(uint2*)(ctx + cbase + d0 * 16 + lq * 4) = w;
  }
}

// -------- LayerNorm: bf16 delta in -> f32 out, rows of 2048 --------
__global__ __launch_bounds__(256)
void ln_kernel(const u16* __restrict__ in, float* __restrict__ out,
               const float* __restrict__ gamma, const float* __restrict__ beta) {
  const int row = blockIdx.x, tid = threadIdx.x;
  const u16* x = in + (size_t)row * 2048;
  const uint4 raw = *(const uint4*)(x + tid * 8);
  float xv[8];
  xv[0] = b2f(raw.x & 0xFFFFu); xv[1] = b2f(raw.x >> 16);
  xv[2] = b2f(raw.y & 0xFFFFu); xv[3] = b2f(raw.y >> 16);
  xv[4] = b2f(raw.z & 0xFFFFu); xv[5] = b2f(raw.z >> 16);
  xv[6] = b2f(raw.w & 0xFFFFu); xv[7] = b2f(raw.w >> 16);
  float s = 0.f, ss = 0.f;
#pragma unroll
  for (int i = 0; i < 8; ++i) { s += xv[i]; ss += xv[i] * xv[i]; }
#pragma unroll
  for (int d = 1; d < 64; d <<= 1) {
    s += __shfl_xor(s, d);
    ss += __shfl_xor(ss, d);
  }
  __shared__ float rbuf[8];
  const int w = tid >> 6;
  if ((tid & 63) == 0) { rbuf[w] = s; rbuf[4 + w] = ss; }
  __syncthreads();
  s = rbuf[0] + rbuf[1] + rbuf[2] + rbuf[3];
  ss = rbuf[4] + rbuf[5] + rbuf[6] + rbuf[7];
  const float mu = s * (1.0f / 2048.0f);
  const float var = ss * (1.0f / 2048.0f) - mu * mu;
  const float inv = rsqrtf(var + 1e-5f);
  const float4 g0 = *(const float4*)(gamma + tid * 8);
  const float4 g1 = *(const float4*)(gamma + tid * 8 + 4);
  const float4 b0 = *(const float4*)(beta + tid * 8);
  const float4 b1 = *(const float4*)(beta + tid * 8 + 4);
  float4 y0, y1;
  y0.x = (xv[0] - mu) * inv * g0.x + b0.x;
  y0.y = (xv[1] - mu) * inv * g0.y + b0.y;
  y0.z = (xv[2] - mu) * inv * g0.z + b0.z;
  y0.w = (xv[3] - mu) * inv * g0.w + b0.w;
  y1.x = (xv[4] - mu) * inv * g1.x + b1.x;
  y1.y = (xv[5] - mu) * inv * g1.y + b1.y;
  y1.z = (xv[6] - mu) * inv * g1.z + b1.z;
  y1.w = (xv[7] - mu) * inv * g1.w + b1.w;
  float* o = out + (size_t)row * 2048 + tid * 8;
  *(float4*)o = y0;
  *(float4*)(o + 4) = y1;
}

extern "C" void kernel_launch(void* const* d_in, const int* in_sizes, int n_in,
                              void* d_out, int out_size, void* d_ws, size_t ws_size,
                              hipStream_t stream) {
  (void)in_sizes; (void)n_in; (void)out_size; (void)ws_size;
  const float* hs = (const float*)d_in[0];
  const float* at = (const float*)d_in[1];
  const int* mask = (const int*)d_in[2];
  const float* Wq = (const float*)d_in[3];
  const float* bq = (const float*)d_in[4];
  const float* Wk = (const float*)d_in[5];
  const float* bk = (const float*)d_in[6];
  const float* Wv = (const float*)d_in[7];
  const float* bv = (const float*)d_in[8];
  const float* Wo = (const float*)d_in[9];
  const float* bo = (const float*)d_in[10];
  const float* lg = (const float*)d_in[11];
  const float* lb = (const float*)d_in[12];
  const float* rs = (const float*)d_in[13];

  // workspace layout (u16 elements); ctx aliases hs_bf (hs dead after Q-GEMM);
  // delta_bf aliases Q_bf (Q dead after attn)
  u16* hs_bf = (u16*)d_ws;              // 16,777,216
  u16* at_bf = hs_bf + 16777216;        //  2,097,152
  u16* Wq_bf = at_bf + 2097152;         //  4,194,304
  u16* Wk_bf = Wq_bf + 4194304;
  u16* Wv_bf = Wk_bf + 4194304;
  u16* Wo_bf = Wv_bf + 4194304;
  u16* Q_bf  = Wo_bf + 4194304;         // 16,777,216
  u16* K_bf  = Q_bf + 16777216;         //  2,097,152
  u16* Vt_bf = K_bf + 2097152;          //  2,097,152  => total 113,246,208 bytes
  u16* ctx_bf = hs_bf;                  // alias
  u16* delta_bf = Q_bf;                 // alias

  cast_all<<<34816, 256, 0, stream>>>(hs, at, Wq, Wk, Wv, Wo,
                                      hs_bf, at_bf, Wq_bf, Wk_bf, Wv_bf, Wo_bf);

  gemm8<0><<<dim3(8, 32), 512, 0, stream>>>(hs_bf, Wq_bf, bq, nullptr, Q_bf);
  gemm_kv<<<dim3(16, 8, 2), 256, 0, stream>>>(at_bf, Wk_bf, Wv_bf, bk, bv, K_bf, Vt_bf);

  attn_kernel<<<dim3(16, 16, 4), 512, 0, stream>>>(Q_bf, K_bf, Vt_bf, mask, ctx_bf);

  gemm8<3><<<dim3(8, 32), 512, 0, stream>>>(ctx_bf, Wo_bf, bo, rs, delta_bf);
  ln_kernel<<<8192, 256, 0, stream>>>(delta_bf, (float*)d_out, lg, lb);
}

// Round 7
// 258.171 us; speedup vs baseline: 5.0104x; 5.0104x over previous
//
#include <hip/hip_runtime.h>
#include <stdint.h>

typedef unsigned short u16;
typedef __attribute__((ext_vector_type(8))) __bf16 bf16x8;
typedef __attribute__((ext_vector_type(4))) float f32x4;

#define AS1 __attribute__((address_space(1)))
#define AS3 __attribute__((address_space(3)))

// Problem constants (hardcoded: B=4, S=2048, T=256, H=2048, NH=16, HD=128)
constexpr int HB = 4;
constexpr int SS = 2048;
constexpr int TT = 256;
constexpr int HH = 2048;
constexpr int NHEAD = 16;
constexpr int HD = 128;

__device__ __forceinline__ u16 f2b(float f) {
  union { float f; uint32_t u; } c; c.f = f;
  return (u16)((c.u + 0x7FFFu + ((c.u >> 16) & 1u)) >> 16);
}

__device__ __forceinline__ float b2f(uint32_t lo16) {
  union { uint32_t u; float f; } c; c.u = lo16 << 16;
  return c.f;
}

// ---------------- all f32 -> bf16 casts in ONE launch ----------------
// regions (in float4-quads/256 blocks): hs 16384, at 2048, Wq/Wk/Wv/Wo 4096 each
__global__ __launch_bounds__(256)
void cast_all(const float* __restrict__ hs, const float* __restrict__ at,
              const float* __restrict__ wq, const float* __restrict__ wk,
              const float* __restrict__ wv, const float* __restrict__ wo,
              u16* __restrict__ o_hs, u16* __restrict__ o_at,
              u16* __restrict__ o_wq, u16* __restrict__ o_wk,
              u16* __restrict__ o_wv, u16* __restrict__ o_wo) {
  const int b = blockIdx.x;
  const float* src; u16* dst; int base;
  if (b < 16384)      { src = hs; dst = o_hs; base = 0; }
  else if (b < 18432) { src = at; dst = o_at; base = 16384; }
  else if (b < 22528) { src = wq; dst = o_wq; base = 18432; }
  else if (b < 26624) { src = wk; dst = o_wk; base = 22528; }
  else if (b < 30720) { src = wv; dst = o_wv; base = 26624; }
  else                { src = wo; dst = o_wo; base = 30720; }
  const size_t i = (size_t)(b - base) * 256 + threadIdx.x;
  const float4 v = *(const float4*)(src + i * 4);
  uint2 pk;
  pk.x = (uint32_t)f2b(v.x) | ((uint32_t)f2b(v.y) << 16);
  pk.y = (uint32_t)f2b(v.z) | ((uint32_t)f2b(v.w) << 16);
  *(uint2*)(dst + i * 4) = pk;
}

// ============ big GEMM (M multiple of 256, N=K=2048) =========================
// BM=256, BN=256, BK=32 slices. 8 waves (2m x 4n), per-wave 128x64 (8x4 frags).
// 4 LDS buffers (128 KB), 1 block/CU, (512,2). v3 schedule: ALL next-slice
// fragment reads issue >=1 MFMA-cluster before first use (B(t+1) before set0,
// A0(t+1) between sets, A1(t+1) after set1) so the slice-top lgkmcnt(4) waits
// on nothing -- fixes the read/MFMA serialization that capped MfmaUtil at 46%.
// bf/bfn role-swap via 2-unrolled loop. vmcnt(0) pre-barrier waits only
// stage(t+2) issued a full slice earlier (~free).
// MODE 0: bf16 out. MODE 2: f32 out * clip(rs). MODE 3: bf16 out * clip(rs).
template<int MODE>
__global__ __launch_bounds__(512, 2)
void gemm8(const u16* __restrict__ A, const u16* __restrict__ Bw,
           const float* __restrict__ bias, const float* __restrict__ rsp,
           void* __restrict__ outp) {
  constexpr int KD = 2048, NT = 64;          // K slices of 32
  constexpr int BUF = 16384;                 // u16 per buffer (A 8192 + B 8192)
  __shared__ u16 lds[4 * BUF];               // 128 KB
  const int tid = threadIdx.x;
  const int wv = tid >> 6, ln = tid & 63;
  const int lq = ln >> 4, lr = ln & 15;
  const int wm = wv >> 2, wn = wv & 3;

  // XCD-bijective block swizzle (nwg = 256, %8 == 0); n fastest within XCD
  const int linb = blockIdx.y * 8 + blockIdx.x;
  const int ns = (linb & 7) * 32 + (linb >> 3);
  const int m0 = (ns >> 3) * 256;
  const int n0 = (ns & 7) * 256;

  // stage source offsets (inverse-swizzled)
  int gOff[2];
#pragma unroll
  for (int c = 0; c < 2; ++c) {
    const int g = c * 512 + tid, sr = g >> 3, s = g & 7, l = s ^ (sr & 7);
    gOff[c] = (2 * sr + (l >> 2)) * KD + (l & 3) * 8;
  }
  const u16* Abase = A + (size_t)m0 * KD;
  const u16* Bbase = Bw + (size_t)n0 * KD;

  // swizzled read offsets (u16), loop-invariant
  int aoff[8], boff[4];
#pragma unroll
  for (int m = 0; m < 8; ++m) {
    const int R = wm * 128 + m * 16 + lr, sr = R >> 1;
    aoff[m] = sr * 64 + ((((R & 1) << 2) + lq) ^ (sr & 7)) * 8;
  }
#pragma unroll
  for (int j = 0; j < 4; ++j) {
    const int R = wn * 64 + j * 16 + lr, sr = R >> 1;
    boff[j] = 8192 + sr * 64 + ((((R & 1) << 2) + lq) ^ (sr & 7)) * 8;
  }

#define STAGE_A(c, k0, buf)                                                      \
  __builtin_amdgcn_global_load_lds((AS1 const void*)(Abase + (k0) + gOff[c]),    \
      (AS3 void*)(lds + (buf) * BUF + ((c) * 512 + wv * 64) * 8), 16, 0, 0)
#define STAGE_B(c, k0, buf)                                                      \
  __builtin_amdgcn_global_load_lds((AS1 const void*)(Bbase + (k0) + gOff[c]),    \
      (AS3 void*)(lds + (buf) * BUF + 8192 + ((c) * 512 + wv * 64) * 8), 16, 0, 0)

  f32x4 acc[8][4];
#pragma unroll
  for (int i = 0; i < 8; ++i)
#pragma unroll
    for (int j = 0; j < 4; ++j) acc[i][j] = (f32x4){0.f, 0.f, 0.f, 0.f};

  // prologue: slices 0,1,2 -> buf0,1,2; wait slices 0,1 (slice 2 in flight)
  STAGE_A(0, 0, 0);  STAGE_A(1, 0, 0);  STAGE_B(0, 0, 0);  STAGE_B(1, 0, 0);
  STAGE_A(0, 32, 1); STAGE_A(1, 32, 1); STAGE_B(0, 32, 1); STAGE_B(1, 32, 1);
  STAGE_A(0, 64, 2); STAGE_A(1, 64, 2); STAGE_B(0, 64, 2); STAGE_B(1, 64, 2);
  asm volatile("s_waitcnt vmcnt(4)" ::: "memory");
  __builtin_amdgcn_s_barrier();
  __builtin_amdgcn_sched_barrier(0);

  // preload ALL slice-0 fragments
  bf16x8 af[4], afn[4], bf[4], bfn[4];
#pragma unroll
  for (int j = 0; j < 4; ++j) bf[j] = *(const bf16x8*)(lds + boff[j]);
#pragma unroll
  for (int m = 0; m < 4; ++m) af[m] = *(const bf16x8*)(lds + aoff[m]);
#pragma unroll
  for (int m = 0; m < 4; ++m) afn[m] = *(const bf16x8*)(lds + aoff[4 + m]);
  __builtin_amdgcn_sched_barrier(0);

  // SLICE(t): entry regs A0=A(t,m0-3), A1=A(t,m4-7), BC=B(t); loads next into
  // BN=B(t+1), A0<-A(t+1,m0-3), A1<-A(t+1,m4-7), each >=1 cluster early.
#define SLICE(t, A0, A1, BC, BN)                                                 \
  {                                                                              \
    const bool nx = (t) + 1 < NT;                                                \
    const u16* nb = lds + (((t) + 1) & 3) * BUF;                                 \
    if (nx) {                                                                    \
      _Pragma("unroll")                                                          \
      for (int j = 0; j < 4; ++j) BN[j] = *(const bf16x8*)(nb + boff[j]);        \
    }                                                                            \
    __builtin_amdgcn_sched_barrier(0);                                           \
    __builtin_amdgcn_s_setprio(1);                                               \
    _Pragma("unroll")                                                            \
    for (int m = 0; m < 4; ++m)                                                  \
      _Pragma("unroll")                                                          \
      for (int j = 0; j < 4; ++j)                                                \
        acc[m][j] = __builtin_amdgcn_mfma_f32_16x16x32_bf16(A0[m], BC[j], acc[m][j], 0, 0, 0); \
    __builtin_amdgcn_s_setprio(0);                                               \
    __builtin_amdgcn_sched_barrier(0);                                           \
    if (nx) {                                                                    \
      _Pragma("unroll")                                                          \
      for (int m = 0; m < 4; ++m) A0[m] = *(const bf16x8*)(nb + aoff[m]);        \
    }                                                                            \
    __builtin_amdgcn_sched_barrier(0);                                           \
    __builtin_amdgcn_s_setprio(1);                                               \
    _Pragma("unroll")                                                            \
    for (int m = 0; m < 4; ++m)                                                  \
      _Pragma("unroll")                                                          \
      for (int j = 0; j < 4; ++j)                                                \
        acc[4 + m][j] = __builtin_amdgcn_mfma_f32_16x16x32_bf16(A1[m], BC[j], acc[4 + m][j], 0, 0, 0); \
    __builtin_amdgcn_s_setprio(0);                                               \
    __builtin_amdgcn_sched_barrier(0);                                           \
    if (nx) {                                                                    \
      _Pragma("unroll")                                                          \
      for (int m = 0; m < 4; ++m) A1[m] = *(const bf16x8*)(nb + aoff[4 + m]);    \
      asm volatile("s_waitcnt lgkmcnt(4)" ::: "memory");  /* BN,A0 retired */    \
    } else {                                                                     \
      asm volatile("s_waitcnt lgkmcnt(0)" ::: "memory");                         \
    }                                                                            \
    asm volatile("s_waitcnt vmcnt(0)" ::: "memory");      /* stage(t+2) landed */\
    __builtin_amdgcn_s_barrier();                                                \
    __builtin_amdgcn_sched_barrier(0);                                           \
    if ((t) + 3 < NT) {                                                          \
      const int k3 = ((t) + 3) * 32, sb = ((t) + 3) & 3;                         \
      STAGE_A(0, k3, sb); STAGE_A(1, k3, sb);                                    \
      STAGE_B(0, k3, sb); STAGE_B(1, k3, sb);                                    \
    }                                                                            \
    __builtin_amdgcn_sched_barrier(0);                                           \
  }

  for (int t = 0; t < NT; t += 2) {
    SLICE(t, af, afn, bf, bfn);
    SLICE(t + 1, af, afn, bfn, bf);
  }
#undef SLICE
#undef STAGE_A
#undef STAGE_B

  float bj[4];
#pragma unroll
  for (int j = 0; j < 4; ++j) bj[j] = bias[n0 + wn * 64 + j * 16 + lr];
  float rsv = 0.f;
  if constexpr (MODE == 2 || MODE == 3) rsv = fminf(fmaxf(rsp[0], 0.0f), 0.3f);

#pragma unroll
  for (int i = 0; i < 8; ++i)
#pragma unroll
    for (int j = 0; j < 4; ++j)
#pragma unroll
      for (int r = 0; r < 4; ++r) {
        const int row = m0 + wm * 128 + i * 16 + lq * 4 + r;  // C/D: row=(lane>>4)*4+reg
        const int col = n0 + wn * 64 + j * 16 + lr;           //      col=lane&15
        const float v = acc[i][j][r] + bj[j];
        if constexpr (MODE == 0) {
          ((u16*)outp)[(size_t)row * 2048 + col] = f2b(v);
        } else if constexpr (MODE == 2) {
          ((float*)outp)[(size_t)row * 2048 + col] = v * rsv;
        } else {
          ((u16*)outp)[(size_t)row * 2048 + col] = f2b(v * rsv);
        }
      }
}

// -------- K+V projection in one launch (M=1024 each) --------
// blockIdx.z==0: K row-major out; z==1: V transposed out (Vt layout).
__global__ __launch_bounds__(256, 2)
void gemm_kv(const u16* __restrict__ A, const u16* __restrict__ Wk,
             const u16* __restrict__ Wv, const float* __restrict__ bkp,
             const float* __restrict__ bvp, u16* __restrict__ Ko,
             u16* __restrict__ Vto) {
  constexpr int KD = 2048, NT = 64;
  constexpr int BUFE = 8192;                 // u16 per slice buffer (A 4096 + B 4096)
  __shared__ u16 lds[4 * BUFE];              // 64 KB
  const bool isV = blockIdx.z != 0;
  const u16* Bw = isV ? Wv : Wk;
  const float* bias = isV ? bvp : bkp;
  const int tid = threadIdx.x;
  const int wave = tid >> 6, lane = tid & 63;
  const int lq = lane >> 4, lr = lane & 15;
  const int wr = wave >> 1, wc = wave & 1;
  const int m0 = blockIdx.y * 128, n0 = blockIdx.x * 128;

  // stage source offsets (inverse-swizzled); g in [0,512) chunks per region
  int gOff[2];
#pragma unroll
  for (int c = 0; c < 2; ++c) {
    const int g = c * 256 + tid, sr = g >> 3, s = g & 7, l = s ^ (sr & 7);
    gOff[c] = (2 * sr + (l >> 2)) * KD + (l & 3) * 8;
  }
  const u16* Abase = A + (size_t)m0 * KD;
  const u16* Bbase = Bw + (size_t)n0 * KD;

  // swizzled read offsets (u16), loop-invariant; 2 lanes/slot -> conflict-free
  int aoff[4], boff[4];
#pragma unroll
  for (int i = 0; i < 4; ++i) {
    const int R = wr * 64 + i * 16 + lr, sr = R >> 1;
    aoff[i] = sr * 64 + ((((R & 1) << 2) + lq) ^ (sr & 7)) * 8;
  }
#pragma unroll
  for (int j = 0; j < 4; ++j) {
    const int R = wc * 64 + j * 16 + lr, sr = R >> 1;
    boff[j] = 4096 + sr * 64 + ((((R & 1) << 2) + lq) ^ (sr & 7)) * 8;
  }

#define KV_STAGE(t3, buf)                                                         \
  {                                                                               \
    _Pragma("unroll")                                                             \
    for (int c_ = 0; c_ < 2; ++c_) {                                              \
      __builtin_amdgcn_global_load_lds(                                           \
          (AS1 const void*)(Abase + (t3) * 32 + gOff[c_]),                        \
          (AS3 void*)(lds + (buf) * BUFE + (c_ * 256 + wave * 64) * 8), 16, 0, 0);\
      __builtin_amdgcn_global_load_lds(                                           \
          (AS1 const void*)(Bbase + (t3) * 32 + gOff[c_]),                        \
          (AS3 void*)(lds + (buf) * BUFE + 4096 + (c_ * 256 + wave * 64) * 8),    \
          16, 0, 0);                                                              \
    }                                                                             \
  }

  f32x4 acc[4][4];
#pragma unroll
  for (int i = 0; i < 4; ++i)
#pragma unroll
    for (int j = 0; j < 4; ++j) acc[i][j] = (f32x4){0.f, 0.f, 0.f, 0.f};

  // prologue: slices 0,1,2 (4 loads each); wait slice 0 only
  KV_STAGE(0, 0); KV_STAGE(1, 1); KV_STAGE(2, 2);
  asm volatile("s_waitcnt vmcnt(8)" ::: "memory");
  __builtin_amdgcn_s_barrier();
  __builtin_amdgcn_sched_barrier(0);

  bf16x8 af[4], bfr[4];
#pragma unroll
  for (int i = 0; i < 4; ++i) af[i] = *(const bf16x8*)(lds + aoff[i]);
#pragma unroll
  for (int j = 0; j < 4; ++j) bfr[j] = *(const bf16x8*)(lds + boff[j]);
  __builtin_amdgcn_sched_barrier(0);

  for (int t = 0; t < NT; ++t) {
    if (t + 3 < NT) KV_STAGE(t + 3, (t + 3) & 3);
    asm volatile("s_waitcnt lgkmcnt(0)" ::: "memory");  // frags(t) ready (pre-barrier)
    __builtin_amdgcn_sched_barrier(0);
    __builtin_amdgcn_s_setprio(1);
#pragma unroll
    for (int i = 0; i < 4; ++i)
#pragma unroll
      for (int j = 0; j < 4; ++j)
        acc[i][j] = __builtin_amdgcn_mfma_f32_16x16x32_bf16(af[i], bfr[j], acc[i][j], 0, 0, 0);
    __builtin_amdgcn_s_setprio(0);
    if (t < NT - 3)       asm volatile("s_waitcnt vmcnt(8)" ::: "memory");
    else if (t == NT - 3) asm volatile("s_waitcnt vmcnt(4)" ::: "memory");
    else                  asm volatile("s_waitcnt vmcnt(0)" ::: "memory");
    __builtin_amdgcn_s_barrier();                       // single barrier per slice
    __builtin_amdgcn_sched_barrier(0);
    if (t + 1 < NT) {
      const u16* bn = lds + ((t + 1) & 3) * BUFE;
#pragma unroll
      for (int i = 0; i < 4; ++i) af[i] = *(const bf16x8*)(bn + aoff[i]);
#pragma unroll
      for (int j = 0; j < 4; ++j) bfr[j] = *(const bf16x8*)(bn + boff[j]);
    }
    __builtin_amdgcn_sched_barrier(0);
  }
#undef KV_STAGE

  float bj[4];
#pragma unroll
  for (int j = 0; j < 4; ++j) bj[j] = bias[n0 + wc * 64 + j * 16 + lr];

#pragma unroll
  for (int i = 0; i < 4; ++i)
#pragma unroll
    for (int j = 0; j < 4; ++j)
#pragma unroll
      for (int r = 0; r < 4; ++r) {
        const int row = m0 + wr * 64 + i * 16 + lq * 4 + r;
        const int col = n0 + wc * 64 + j * 16 + lr;
        const float v = acc[i][j][r] + bj[j];
        if (!isV) {
          Ko[(size_t)row * 2048 + col] = f2b(v);
        } else {
          Vto[(size_t)(row >> 8) * (2048 * 256) + (size_t)col * 256 + (row & 255)] = f2b(v);
        }
      }
}

// ---------------- fused cross-attention, v6: chunked + max-free softmax -----
// Proven v3 structure (grid (S/128, NH, B), 512 threads, K/V double-buffered
// LDS, counted vmcnt, per-chunk sc[4] only -> no spill) + max-free softmax:
// scores pre-clipped to [-50,50] => exp/sum f32-safe without max subtraction,
// p/sum == softmax exactly. Sum is a local accumulator reduced once at end.
__global__ __launch_bounds__(512, 4)
void attn_kernel(const u16* __restrict__ Q, const u16* __restrict__ Kb,
                 const u16* __restrict__ Vt, const int* __restrict__ mask,
                 u16* __restrict__ ctx) {
  __shared__ u16 sK[2][64 * 128];   // 2x16 KB, swz slot^(row&15)
  __shared__ u16 sVt[2][128 * 64];  // 2x16 KB, swz slot^(row&7)
  __shared__ u16 sP[8 * 16 * 64];   // 16 KB per-wave P quarter, XOR swz

  const int tid = threadIdx.x;
  const int wv = tid >> 6, ln = tid & 63;
  const int lq = ln >> 4, lr = ln & 15;
  const int h = blockIdx.y, b = blockIdx.z;
  const int s0blk = blockIdx.x * 128;
  u16* sPw = sP + wv * (16 * 64);

  // mask bits for lane lr: bit g = attend(t = g*16 + lr), g = c*4 + tt
  uint32_t mbits = 0;
#pragma unroll
  for (int g = 0; g < 16; ++g)
    mbits |= (mask[b * TT + g * 16 + lr] != 0 ? 1u : 0u) << g;

  // ---- Q fragments direct from global (loop-invariant) ----
  bf16x8 qf[4];
  {
    const u16* qp = Q + ((size_t)b * SS + s0blk + wv * 16 + lr) * HH + (size_t)h * HD + lq * 8;
#pragma unroll
    for (int kd = 0; kd < 4; ++kd) qf[kd] = *(const bf16x8*)(qp + kd * 32);
  }

#define STAGE_KV(c)                                                                      \
  {                                                                                      \
    const int buf_ = (c) & 1;                                                            \
    _Pragma("unroll")                                                                    \
    for (int it = 0; it < 2; ++it) {                                                     \
      const int ub = it * 512 + wv * 64;                                                 \
      const int u = ub + ln;                                                             \
      const int row = u >> 4, slot = u & 15, src = slot ^ (row & 15);                    \
      const u16* g = Kb + ((size_t)b * TT + (c) * 64 + row) * HH + h * HD + src * 8;     \
      __builtin_amdgcn_global_load_lds((AS1 const void*)g,                               \
          (AS3 void*)(sK[buf_] + (size_t)ub * 8), 16, 0, 0);                             \
    }                                                                                    \
    _Pragma("unroll")                                                                    \
    for (int it = 0; it < 2; ++it) {                                                     \
      const int ub = it * 512 + wv * 64;                                                 \
      const int u = ub + ln;                                                             \
      const int row = u >> 3, slot = u & 7, src = slot ^ (row & 7);                      \
      const u16* g = Vt + ((size_t)b * HH + h * HD + row) * TT + (c) * 64 + src * 8;     \
      __builtin_amdgcn_global_load_lds((AS1 const void*)g,                               \
          (AS3 void*)(sVt[buf_] + (size_t)ub * 8), 16, 0, 0);                            \
    }                                                                                    \
  }
  STAGE_KV(0);
  STAGE_KV(1);

  const float scale = 0.08838834764831845f;  // 1/sqrt(128)
  float ls[4] = {0.f, 0.f, 0.f, 0.f};       // per-lane partial softmax denom
  f32x4 o[8];  // ctx^T fragments: row d = lq*4+r within d0-tile, col q = lr
#pragma unroll
  for (int d0 = 0; d0 < 8; ++d0) o[d0] = (f32x4){0.f, 0.f, 0.f, 0.f};

  const int qrow = wv * 16 + lr;
  const int shsrc = ((lr >> 2) << 4) + lr;  // lane with lq = lr>>2 for q=lr state

  for (int c = 0; c < 4; ++c) {
    const int buf = c & 1;
    // chunk c landed when <= 4 loads (chunk c+1) outstanding
    if (c < 3) asm volatile("s_waitcnt vmcnt(4)" ::: "memory");
    else       asm volatile("s_waitcnt vmcnt(0)" ::: "memory");
    __syncthreads();

    // ---- QK^T: 4 t-tiles x K=128 (Q frags resident in registers) ----
    f32x4 sc[4];
#pragma unroll
    for (int tt = 0; tt < 4; ++tt) {
      f32x4 a = (f32x4){0.f, 0.f, 0.f, 0.f};
#pragma unroll
      for (int kd = 0; kd < 4; ++kd) {
        bf16x8 kf = *(const bf16x8*)(sK[buf] + (size_t)(tt * 16 + lr) * 128 + (size_t)((kd * 4 + lq) ^ lr) * 8);
        a = __builtin_amdgcn_mfma_f32_16x16x32_bf16(qf[kd], kf, a, 0, 0, 0);
      }
      sc[tt] = a;
    }

    // ---- scale/clip/mask -> exp (max-free) -> local sum accumulate ----
#pragma unroll
    for (int tt = 0; tt < 4; ++tt) {
      const bool on = (mbits >> (c * 4 + tt)) & 1;
#pragma unroll
      for (int r = 0; r < 4; ++r) {
        float v = sc[tt][r] * scale;
        v = fminf(fmaxf(v, -50.f), 50.f);
        v = on ? v : -50.f;
        const float p = __expf(v);
        sc[tt][r] = p;
        ls[r] += p;
      }
    }

    // ---- P (C-layout) -> per-wave LDS (XOR swz, 16B slots) -> fragments ----
#pragma unroll
    for (int tt = 0; tt < 4; ++tt)
#pragma unroll
      for (int r = 0; r < 4; ++r) {
        const int q = lq * 4 + r;
        const int slot = (tt * 2 + (lr >> 3)) ^ ((q >> 1) & 7);
        sPw[(size_t)q * 64 + slot * 8 + (lr & 7)] = f2b(sc[tt][r]);
      }

    bf16x8 pf[2];
#pragma unroll
    for (int kt = 0; kt < 2; ++kt) {
      const int slot = (kt * 4 + lq) ^ ((lr >> 1) & 7);
      pf[kt] = *(const bf16x8*)(sPw + (size_t)lr * 64 + slot * 8);
    }

    // ---- PV transposed: o^T[d][q] += Vt_A . P^T_B ----
#pragma unroll
    for (int d0 = 0; d0 < 8; ++d0)
#pragma unroll
      for (int kt = 0; kt < 2; ++kt) {
        bf16x8 vf = *(const bf16x8*)(sVt[buf] + (size_t)(d0 * 16 + lr) * 64 + (size_t)((kt * 4 + lq) ^ (lr & 7)) * 8);
        o[d0] = __builtin_amdgcn_mfma_f32_16x16x32_bf16(vf, pf[kt], o[d0], 0, 0, 0);
      }
    if (c < 2) {
      __syncthreads();  // all waves done with buf before restaging it
      STAGE_KV(c + 2);
    }
  }
#undef STAGE_KV

  // ---- single sum reduce across lr, then 1/l redistributed to q=lr ----
#pragma unroll
  for (int d = 1; d < 16; d <<= 1)
#pragma unroll
    for (int r = 0; r < 4; ++r) ls[r] += __shfl_xor(ls[r], d);

  const float i0 = __shfl(1.0f / ls[0], shsrc), i1 = __shfl(1.0f / ls[1], shsrc);
  const float i2 = __shfl(1.0f / ls[2], shsrc), i3 = __shfl(1.0f / ls[3], shsrc);
  const int rsel = lr & 3;
  const float iq = rsel == 0 ? i0 : rsel == 1 ? i1 : rsel == 2 ? i2 : i3;

  // ctx[q][d]: lane holds q = s0blk + wv*16 + lr, d = d0*16 + lq*4 + r
  const size_t cbase = ((size_t)b * SS + s0blk + wv * 16 + lr) * HH + (size_t)h * HD;
#pragma unroll
  for (int d0 = 0; d0 < 8; ++d0) {
    uint2 w;
    w.x = (uint32_t)f2b(o[d0][0] * iq) | ((uint32_t)f2b(o[d0][1] * iq) << 16);
    w.y = (uint32_t)f2b(o[d0][2] * iq) | ((uint32_t)f2b(o[d0][3] * iq) << 16);
    *(uint2*)(ctx + cbase + d0 * 16 + lq * 4) = w;
  }
}

// -------- LayerNorm: bf16 delta in -> f32 out, rows of 2048 --------
__global__ __launch_bounds__(256)
void ln_kernel(const u16* __restrict__ in, float* __restrict__ out,
               const float* __restrict__ gamma, const float* __restrict__ beta) {
  const int row = blockIdx.x, tid = threadIdx.x;
  const u16* x = in + (size_t)row * 2048;
  const uint4 raw = *(const uint4*)(x + tid * 8);
  float xv[8];
  xv[0] = b2f(raw.x & 0xFFFFu); xv[1] = b2f(raw.x >> 16);
  xv[2] = b2f(raw.y & 0xFFFFu); xv[3] = b2f(raw.y >> 16);
  xv[4] = b2f(raw.z & 0xFFFFu); xv[5] = b2f(raw.z >> 16);
  xv[6] = b2f(raw.w & 0xFFFFu); xv[7] = b2f(raw.w >> 16);
  float s = 0.f, ss = 0.f;
#pragma unroll
  for (int i = 0; i < 8; ++i) { s += xv[i]; ss += xv[i] * xv[i]; }
#pragma unroll
  for (int d = 1; d < 64; d <<= 1) {
    s += __shfl_xor(s, d);
    ss += __shfl_xor(ss, d);
  }
  __shared__ float rbuf[8];
  const int w = tid >> 6;
  if ((tid & 63) == 0) { rbuf[w] = s; rbuf[4 + w] = ss; }
  __syncthreads();
  s = rbuf[0] + rbuf[1] + rbuf[2] + rbuf[3];
  ss = rbuf[4] + rbuf[5] + rbuf[6] + rbuf[7];
  const float mu = s * (1.0f / 2048.0f);
  const float var = ss * (1.0f / 2048.0f) - mu * mu;
  const float inv = rsqrtf(var + 1e-5f);
  const float4 g0 = *(const float4*)(gamma + tid * 8);
  const float4 g1 = *(const float4*)(gamma + tid * 8 + 4);
  const float4 b0 = *(const float4*)(beta + tid * 8);
  const float4 b1 = *(const float4*)(beta + tid * 8 + 4);
  float4 y0, y1;
  y0.x = (xv[0] - mu) * inv * g0.x + b0.x;
  y0.y = (xv[1] - mu) * inv * g0.y + b0.y;
  y0.z = (xv[2] - mu) * inv * g0.z + b0.z;
  y0.w = (xv[3] - mu) * inv * g0.w + b0.w;
  y1.x = (xv[4] - mu) * inv * g1.x + b1.x;
  y1.y = (xv[5] - mu) * inv * g1.y + b1.y;
  y1.z = (xv[6] - mu) * inv * g1.z + b1.z;
  y1.w = (xv[7] - mu) * inv * g1.w + b1.w;
  float* o = out + (size_t)row * 2048 + tid * 8;
  *(float4*)o = y0;
  *(float4*)(o + 4) = y1;
}

extern "C" void kernel_launch(void* const* d_in, const int* in_sizes, int n_in,
                              void* d_out, int out_size, void* d_ws, size_t ws_size,
                              hipStream_t stream) {
  (void)in_sizes; (void)n_in; (void)out_size; (void)ws_size;
  const float* hs = (const float*)d_in[0];
  const float* at = (const float*)d_in[1];
  const int* mask = (const int*)d_in[2];
  const float* Wq = (const float*)d_in[3];
  const float* bq = (const float*)d_in[4];
  const float* Wk = (const float*)d_in[5];
  const float* bk = (const float*)d_in[6];
  const float* Wv = (const float*)d_in[7];
  const float* bv = (const float*)d_in[8];
  const float* Wo = (const float*)d_in[9];
  const float* bo = (const float*)d_in[10];
  const float* lg = (const float*)d_in[11];
  const float* lb = (const float*)d_in[12];
  const float* rs = (const float*)d_in[13];

  // workspace layout (u16 elements); ctx aliases hs_bf (hs dead after Q-GEMM);
  // delta_bf aliases Q_bf (Q dead after attn)
  u16* hs_bf = (u16*)d_ws;              // 16,777,216
  u16* at_bf = hs_bf + 16777216;        //  2,097,152
  u16* Wq_bf = at_bf + 2097152;         //  4,194,304
  u16* Wk_bf = Wq_bf + 4194304;
  u16* Wv_bf = Wk_bf + 4194304;
  u16* Wo_bf = Wv_bf + 4194304;
  u16* Q_bf  = Wo_bf + 4194304;         // 16,777,216
  u16* K_bf  = Q_bf + 16777216;         //  2,097,152
  u16* Vt_bf = K_bf + 2097152;          //  2,097,152  => total 113,246,208 bytes
  u16* ctx_bf = hs_bf;                  // alias
  u16* delta_bf = Q_bf;                 // alias

  cast_all<<<34816, 256, 0, stream>>>(hs, at, Wq, Wk, Wv, Wo,
                                      hs_bf, at_bf, Wq_bf, Wk_bf, Wv_bf, Wo_bf);

  gemm8<0><<<dim3(8, 32), 512, 0, stream>>>(hs_bf, Wq_bf, bq, nullptr, Q_bf);
  gemm_kv<<<dim3(16, 8, 2), 256, 0, stream>>>(at_bf, Wk_bf, Wv_bf, bk, bv, K_bf, Vt_bf);

  attn_kernel<<<dim3(16, 16, 4), 512, 0, stream>>>(Q_bf, K_bf, Vt_bf, mask, ctx_bf);

  gemm8<3><<<dim3(8, 32), 512, 0, stream>>>(ctx_bf, Wo_bf, bo, rs, delta_bf);
  ln_kernel<<<8192, 256, 0, stream>>>(delta_bf, (float*)d_out, lg, lb);
}

// Round 9
// 247.182 us; speedup vs baseline: 5.2331x; 1.0445x over previous
//
#include <hip/hip_runtime.h>
#include <stdint.h>

typedef unsigned short u16;
typedef __attribute__((ext_vector_type(8))) __bf16 bf16x8;
typedef __attribute__((ext_vector_type(4))) float f32x4;

#define AS1 __attribute__((address_space(1)))
#define AS3 __attribute__((address_space(3)))

// Problem constants (hardcoded: B=4, S=2048, T=256, H=2048, NH=16, HD=128)
constexpr int HB = 4;
constexpr int SS = 2048;
constexpr int TT = 256;
constexpr int HH = 2048;
constexpr int NHEAD = 16;
constexpr int HD = 128;

__device__ __forceinline__ u16 f2b(float f) {
  union { float f; uint32_t u; } c; c.f = f;
  return (u16)((c.u + 0x7FFFu + ((c.u >> 16) & 1u)) >> 16);
}

__device__ __forceinline__ float b2f(uint32_t lo16) {
  union { uint32_t u; float f; } c; c.u = lo16 << 16;
  return c.f;
}

// ---------------- all f32 -> bf16 casts in ONE launch ----------------
// regions (in float4-quads/256 blocks): hs 16384, at 2048, Wq/Wk/Wv/Wo 4096 each
__global__ __launch_bounds__(256)
void cast_all(const float* __restrict__ hs, const float* __restrict__ at,
              const float* __restrict__ wq, const float* __restrict__ wk,
              const float* __restrict__ wv, const float* __restrict__ wo,
              u16* __restrict__ o_hs, u16* __restrict__ o_at,
              u16* __restrict__ o_wq, u16* __restrict__ o_wk,
              u16* __restrict__ o_wv, u16* __restrict__ o_wo) {
  const int b = blockIdx.x;
  const float* src; u16* dst; int base;
  if (b < 16384)      { src = hs; dst = o_hs; base = 0; }
  else if (b < 18432) { src = at; dst = o_at; base = 16384; }
  else if (b < 22528) { src = wq; dst = o_wq; base = 18432; }
  else if (b < 26624) { src = wk; dst = o_wk; base = 22528; }
  else if (b < 30720) { src = wv; dst = o_wv; base = 26624; }
  else                { src = wo; dst = o_wo; base = 30720; }
  const size_t i = (size_t)(b - base) * 256 + threadIdx.x;
  const float4 v = *(const float4*)(src + i * 4);
  uint2 pk;
  pk.x = (uint32_t)f2b(v.x) | ((uint32_t)f2b(v.y) << 16);
  pk.y = (uint32_t)f2b(v.z) | ((uint32_t)f2b(v.w) << 16);
  *(uint2*)(dst + i * 4) = pk;
}

// ============ big GEMM (M multiple of 256, N=K=2048) =========================
// BM=256, BN=256, BK=32 slices. 8 waves (2m x 4n), per-wave 128x64 (8x4 frags).
// 4 LDS buffers (128 KB), stage distance 3, counted vmcnt(8), ONE barrier per
// slice, fragment reads software-pipelined one phase ahead so ds_read drains
// under the MFMA clusters. (Round-5 verified configuration — 62.3 us/dispatch,
// MfmaUtil 46%, no spill. Reorder attempts regressed (r7) or raced (r8).)
// MODE 0: bf16 out. MODE 2: f32 out * clip(rs). MODE 3: bf16 out * clip(rs).
template<int MODE>
__global__ __launch_bounds__(512, 2)
void gemm8(const u16* __restrict__ A, const u16* __restrict__ Bw,
           const float* __restrict__ bias, const float* __restrict__ rsp,
           void* __restrict__ outp) {
  constexpr int KD = 2048, NT = 64;          // K slices of 32
  constexpr int BUF = 16384;                 // u16 per buffer (A 8192 + B 8192)
  __shared__ u16 lds[4 * BUF];               // 128 KB
  const int tid = threadIdx.x;
  const int wv = tid >> 6, ln = tid & 63;
  const int lq = ln >> 4, lr = ln & 15;
  const int wm = wv >> 2, wn = wv & 3;

  // XCD-bijective block swizzle (nwg = 256, %8 == 0); n fastest within XCD
  const int linb = blockIdx.y * 8 + blockIdx.x;
  const int ns = (linb & 7) * 32 + (linb >> 3);
  const int m0 = (ns >> 3) * 256;
  const int n0 = (ns & 7) * 256;

  // stage source offsets (inverse-swizzled)
  int gOff[2];
#pragma unroll
  for (int c = 0; c < 2; ++c) {
    const int g = c * 512 + tid, sr = g >> 3, s = g & 7, l = s ^ (sr & 7);
    gOff[c] = (2 * sr + (l >> 2)) * KD + (l & 3) * 8;
  }
  const u16* Abase = A + (size_t)m0 * KD;
  const u16* Bbase = Bw + (size_t)n0 * KD;

  // swizzled read offsets (u16), loop-invariant
  int aoff[8], boff[4];
#pragma unroll
  for (int m = 0; m < 8; ++m) {
    const int R = wm * 128 + m * 16 + lr, sr = R >> 1;
    aoff[m] = sr * 64 + ((((R & 1) << 2) + lq) ^ (sr & 7)) * 8;
  }
#pragma unroll
  for (int j = 0; j < 4; ++j) {
    const int R = wn * 64 + j * 16 + lr, sr = R >> 1;
    boff[j] = 8192 + sr * 64 + ((((R & 1) << 2) + lq) ^ (sr & 7)) * 8;
  }

#define STAGE_A(c, k0, buf)                                                      \
  __builtin_amdgcn_global_load_lds((AS1 const void*)(Abase + (k0) + gOff[c]),    \
      (AS3 void*)(lds + (buf) * BUF + ((c) * 512 + wv * 64) * 8), 16, 0, 0)
#define STAGE_B(c, k0, buf)                                                      \
  __builtin_amdgcn_global_load_lds((AS1 const void*)(Bbase + (k0) + gOff[c]),    \
      (AS3 void*)(lds + (buf) * BUF + 8192 + ((c) * 512 + wv * 64) * 8), 16, 0, 0)

  f32x4 acc[8][4];
#pragma unroll
  for (int i = 0; i < 8; ++i)
#pragma unroll
    for (int j = 0; j < 4; ++j) acc[i][j] = (f32x4){0.f, 0.f, 0.f, 0.f};

  // prologue: slices 0,1,2 -> buf0,1,2 (4 loads/thread each); wait slice 0 only
  STAGE_A(0, 0, 0);  STAGE_A(1, 0, 0);  STAGE_B(0, 0, 0);  STAGE_B(1, 0, 0);
  STAGE_A(0, 32, 1); STAGE_A(1, 32, 1); STAGE_B(0, 32, 1); STAGE_B(1, 32, 1);
  STAGE_A(0, 64, 2); STAGE_A(1, 64, 2); STAGE_B(0, 64, 2); STAGE_B(1, 64, 2);
  asm volatile("s_waitcnt vmcnt(8)" ::: "memory");
  __builtin_amdgcn_s_barrier();
  __builtin_amdgcn_sched_barrier(0);

  // preload slice-0 fragments (P0: B all 4, A m0-3)
  bf16x8 af[4], bf[4], afn[4];
#pragma unroll
  for (int j = 0; j < 4; ++j) bf[j] = *(const bf16x8*)(lds + boff[j]);
#pragma unroll
  for (int m = 0; m < 4; ++m) af[m] = *(const bf16x8*)(lds + aoff[m]);
  __builtin_amdgcn_sched_barrier(0);

  for (int t = 0; t < NT; ++t) {
    const u16* bb = lds + (t & 3) * BUF;
    const u16* bn = lds + ((t + 1) & 3) * BUF;
    const int stg = (t + 3) & 3;
    const int k3 = (t + 3) * 32;
    const bool doStage = (t + 3) < NT;

    // P1 reads of current slice (A m4-7) -> drain under MFMA set0
#pragma unroll
    for (int m = 0; m < 4; ++m) afn[m] = *(const bf16x8*)(bb + aoff[4 + m]);
    if (doStage) { STAGE_A(0, k3, stg); STAGE_A(1, k3, stg); }
    asm volatile("s_waitcnt lgkmcnt(4)" ::: "memory");  // af,bf ready; afn in flight
    __builtin_amdgcn_sched_barrier(0);
    __builtin_amdgcn_s_setprio(1);
#pragma unroll
    for (int m = 0; m < 4; ++m)
#pragma unroll
      for (int j = 0; j < 4; ++j)
        acc[m][j] = __builtin_amdgcn_mfma_f32_16x16x32_bf16(af[m], bf[j], acc[m][j], 0, 0, 0);
    __builtin_amdgcn_s_setprio(0);
    if (doStage) { STAGE_B(0, k3, stg); STAGE_B(1, k3, stg); }
    if (t < NT - 3)       asm volatile("s_waitcnt vmcnt(8)" ::: "memory");
    else if (t == NT - 3) asm volatile("s_waitcnt vmcnt(4)" ::: "memory");
    else                  asm volatile("s_waitcnt vmcnt(0)" ::: "memory");
    asm volatile("s_waitcnt lgkmcnt(0)" ::: "memory");  // afn done BEFORE barrier
    __builtin_amdgcn_s_barrier();                        // single barrier per slice
    __builtin_amdgcn_sched_barrier(0);
    // next-slice P0 A reads -> drain under MFMA set1
    if (t + 1 < NT) {
#pragma unroll
      for (int m = 0; m < 4; ++m) af[m] = *(const bf16x8*)(bn + aoff[m]);
    }
    __builtin_amdgcn_s_setprio(1);
#pragma unroll
    for (int m = 0; m < 4; ++m)
#pragma unroll
      for (int j = 0; j < 4; ++j)
        acc[4 + m][j] = __builtin_amdgcn_mfma_f32_16x16x32_bf16(afn[m], bf[j], acc[4 + m][j], 0, 0, 0);
    __builtin_amdgcn_s_setprio(0);
    // next-slice B reads -> drain under next slice head; must precede next afn
    if (t + 1 < NT) {
#pragma unroll
      for (int j = 0; j < 4; ++j) bf[j] = *(const bf16x8*)(bn + boff[j]);
    }
    __builtin_amdgcn_sched_barrier(0);
  }
#undef STAGE_A
#undef STAGE_B

  float bj[4];
#pragma unroll
  for (int j = 0; j < 4; ++j) bj[j] = bias[n0 + wn * 64 + j * 16 + lr];
  float rsv = 0.f;
  if constexpr (MODE == 2 || MODE == 3) rsv = fminf(fmaxf(rsp[0], 0.0f), 0.3f);

#pragma unroll
  for (int i = 0; i < 8; ++i)
#pragma unroll
    for (int j = 0; j < 4; ++j)
#pragma unroll
      for (int r = 0; r < 4; ++r) {
        const int row = m0 + wm * 128 + i * 16 + lq * 4 + r;  // C/D: row=(lane>>4)*4+reg
        const int col = n0 + wn * 64 + j * 16 + lr;           //      col=lane&15
        const float v = acc[i][j][r] + bj[j];
        if constexpr (MODE == 0) {
          ((u16*)outp)[(size_t)row * 2048 + col] = f2b(v);
        } else if constexpr (MODE == 2) {
          ((float*)outp)[(size_t)row * 2048 + col] = v * rsv;
        } else {
          ((u16*)outp)[(size_t)row * 2048 + col] = f2b(v * rsv);
        }
      }
}

// -------- K+V projection in one launch (M=1024 each) --------
// blockIdx.z==0: K row-major out; z==1: V transposed out (Vt layout).
__global__ __launch_bounds__(256, 2)
void gemm_kv(const u16* __restrict__ A, const u16* __restrict__ Wk,
             const u16* __restrict__ Wv, const float* __restrict__ bkp,
             const float* __restrict__ bvp, u16* __restrict__ Ko,
             u16* __restrict__ Vto) {
  constexpr int KD = 2048, NT = 64;
  constexpr int BUFE = 8192;                 // u16 per slice buffer (A 4096 + B 4096)
  __shared__ u16 lds[4 * BUFE];              // 64 KB
  const bool isV = blockIdx.z != 0;
  const u16* Bw = isV ? Wv : Wk;
  const float* bias = isV ? bvp : bkp;
  const int tid = threadIdx.x;
  const int wave = tid >> 6, lane = tid & 63;
  const int lq = lane >> 4, lr = lane & 15;
  const int wr = wave >> 1, wc = wave & 1;
  const int m0 = blockIdx.y * 128, n0 = blockIdx.x * 128;

  // stage source offsets (inverse-swizzled); g in [0,512) chunks per region
  int gOff[2];
#pragma unroll
  for (int c = 0; c < 2; ++c) {
    const int g = c * 256 + tid, sr = g >> 3, s = g & 7, l = s ^ (sr & 7);
    gOff[c] = (2 * sr + (l >> 2)) * KD + (l & 3) * 8;
  }
  const u16* Abase = A + (size_t)m0 * KD;
  const u16* Bbase = Bw + (size_t)n0 * KD;

  // swizzled read offsets (u16), loop-invariant; 2 lanes/slot -> conflict-free
  int aoff[4], boff[4];
#pragma unroll
  for (int i = 0; i < 4; ++i) {
    const int R = wr * 64 + i * 16 + lr, sr = R >> 1;
    aoff[i] = sr * 64 + ((((R & 1) << 2) + lq) ^ (sr & 7)) * 8;
  }
#pragma unroll
  for (int j = 0; j < 4; ++j) {
    const int R = wc * 64 + j * 16 + lr, sr = R >> 1;
    boff[j] = 4096 + sr * 64 + ((((R & 1) << 2) + lq) ^ (sr & 7)) * 8;
  }

#define KV_STAGE(t3, buf)                                                         \
  {                                                                               \
    _Pragma("unroll")                                                             \
    for (int c_ = 0; c_ < 2; ++c_) {                                              \
      __builtin_amdgcn_global_load_lds(                                           \
          (AS1 const void*)(Abase + (t3) * 32 + gOff[c_]),                        \
          (AS3 void*)(lds + (buf) * BUFE + (c_ * 256 + wave * 64) * 8), 16, 0, 0);\
      __builtin_amdgcn_global_load_lds(                                           \
          (AS1 const void*)(Bbase + (t3) * 32 + gOff[c_]),                        \
          (AS3 void*)(lds + (buf) * BUFE + 4096 + (c_ * 256 + wave * 64) * 8),    \
          16, 0, 0);                                                              \
    }                                                                             \
  }

  f32x4 acc[4][4];
#pragma unroll
  for (int i = 0; i < 4; ++i)
#pragma unroll
    for (int j = 0; j < 4; ++j) acc[i][j] = (f32x4){0.f, 0.f, 0.f, 0.f};

  // prologue: slices 0,1,2 (4 loads each); wait slice 0 only
  KV_STAGE(0, 0); KV_STAGE(1, 1); KV_STAGE(2, 2);
  asm volatile("s_waitcnt vmcnt(8)" ::: "memory");
  __builtin_amdgcn_s_barrier();
  __builtin_amdgcn_sched_barrier(0);

  bf16x8 af[4], bfr[4];
#pragma unroll
  for (int i = 0; i < 4; ++i) af[i] = *(const bf16x8*)(lds + aoff[i]);
#pragma unroll
  for (int j = 0; j < 4; ++j) bfr[j] = *(const bf16x8*)(lds + boff[j]);
  __builtin_amdgcn_sched_barrier(0);

  for (int t = 0; t < NT; ++t) {
    if (t + 3 < NT) KV_STAGE(t + 3, (t + 3) & 3);
    asm volatile("s_waitcnt lgkmcnt(0)" ::: "memory");  // frags(t) ready (pre-barrier)
    __builtin_amdgcn_sched_barrier(0);
    __builtin_amdgcn_s_setprio(1);
#pragma unroll
    for (int i = 0; i < 4; ++i)
#pragma unroll
      for (int j = 0; j < 4; ++j)
        acc[i][j] = __builtin_amdgcn_mfma_f32_16x16x32_bf16(af[i], bfr[j], acc[i][j], 0, 0, 0);
    __builtin_amdgcn_s_setprio(0);
    if (t < NT - 3)       asm volatile("s_waitcnt vmcnt(8)" ::: "memory");
    else if (t == NT - 3) asm volatile("s_waitcnt vmcnt(4)" ::: "memory");
    else                  asm volatile("s_waitcnt vmcnt(0)" ::: "memory");
    __builtin_amdgcn_s_barrier();                       // single barrier per slice
    __builtin_amdgcn_sched_barrier(0);
    if (t + 1 < NT) {
      const u16* bn = lds + ((t + 1) & 3) * BUFE;
#pragma unroll
      for (int i = 0; i < 4; ++i) af[i] = *(const bf16x8*)(bn + aoff[i]);
#pragma unroll
      for (int j = 0; j < 4; ++j) bfr[j] = *(const bf16x8*)(bn + boff[j]);
    }
    __builtin_amdgcn_sched_barrier(0);
  }
#undef KV_STAGE

  float bj[4];
#pragma unroll
  for (int j = 0; j < 4; ++j) bj[j] = bias[n0 + wc * 64 + j * 16 + lr];

#pragma unroll
  for (int i = 0; i < 4; ++i)
#pragma unroll
    for (int j = 0; j < 4; ++j)
#pragma unroll
      for (int r = 0; r < 4; ++r) {
        const int row = m0 + wr * 64 + i * 16 + lq * 4 + r;
        const int col = n0 + wc * 64 + j * 16 + lr;
        const float v = acc[i][j][r] + bj[j];
        if (!isV) {
          Ko[(size_t)row * 2048 + col] = f2b(v);
        } else {
          Vto[(size_t)(row >> 8) * (2048 * 256) + (size_t)col * 256 + (row & 255)] = f2b(v);
        }
      }
}

// ---------------- fused cross-attention, v6: chunked + max-free softmax -----
// Proven v3 structure (grid (S/128, NH, B), 512 threads, K/V double-buffered
// LDS, counted vmcnt, per-chunk sc[4] only -> no spill) + max-free softmax:
// scores pre-clipped to [-50,50] => exp/sum f32-safe without max subtraction,
// p/sum == softmax exactly. Sum is a local accumulator reduced once at end.
__global__ __launch_bounds__(512, 4)
void attn_kernel(const u16* __restrict__ Q, const u16* __restrict__ Kb,
                 const u16* __restrict__ Vt, const int* __restrict__ mask,
                 u16* __restrict__ ctx) {
  __shared__ u16 sK[2][64 * 128];   // 2x16 KB, swz slot^(row&15)
  __shared__ u16 sVt[2][128 * 64];  // 2x16 KB, swz slot^(row&7)
  __shared__ u16 sP[8 * 16 * 64];   // 16 KB per-wave P quarter, XOR swz

  const int tid = threadIdx.x;
  const int wv = tid >> 6, ln = tid & 63;
  const int lq = ln >> 4, lr = ln & 15;
  const int h = blockIdx.y, b = blockIdx.z;
  const int s0blk = blockIdx.x * 128;
  u16* sPw = sP + wv * (16 * 64);

  // mask bits for lane lr: bit g = attend(t = g*16 + lr), g = c*4 + tt
  uint32_t mbits = 0;
#pragma unroll
  for (int g = 0; g < 16; ++g)
    mbits |= (mask[b * TT + g * 16 + lr] != 0 ? 1u : 0u) << g;

  // ---- Q fragments direct from global (loop-invariant) ----
  bf16x8 qf[4];
  {
    const u16* qp = Q + ((size_t)b * SS + s0blk + wv * 16 + lr) * HH + (size_t)h * HD + lq * 8;
#pragma unroll
    for (int kd = 0; kd < 4; ++kd) qf[kd] = *(const bf16x8*)(qp + kd * 32);
  }

#define STAGE_KV(c)                                                                      \
  {                                                                                      \
    const int buf_ = (c) & 1;                                                            \
    _Pragma("unroll")                                                                    \
    for (int it = 0; it < 2; ++it) {                                                     \
      const int ub = it * 512 + wv * 64;                                                 \
      const int u = ub + ln;                                                             \
      const int row = u >> 4, slot = u & 15, src = slot ^ (row & 15);                    \
      const u16* g = Kb + ((size_t)b * TT + (c) * 64 + row) * HH + h * HD + src * 8;     \
      __builtin_amdgcn_global_load_lds((AS1 const void*)g,                               \
          (AS3 void*)(sK[buf_] + (size_t)ub * 8), 16, 0, 0);                             \
    }                                                                                    \
    _Pragma("unroll")                                                                    \
    for (int it = 0; it < 2; ++it) {                                                     \
      const int ub = it * 512 + wv * 64;                                                 \
      const int u = ub + ln;                                                             \
      const int row = u >> 3, slot = u & 7, src = slot ^ (row & 7);                      \
      const u16* g = Vt + ((size_t)b * HH + h * HD + row) * TT + (c) * 64 + src * 8;     \
      __builtin_amdgcn_global_load_lds((AS1 const void*)g,                               \
          (AS3 void*)(sVt[buf_] + (size_t)ub * 8), 16, 0, 0);                            \
    }                                                                                    \
  }
  STAGE_KV(0);
  STAGE_KV(1);

  const float scale = 0.08838834764831845f;  // 1/sqrt(128)
  float ls[4] = {0.f, 0.f, 0.f, 0.f};       // per-lane partial softmax denom
  f32x4 o[8];  // ctx^T fragments: row d = lq*4+r within d0-tile, col q = lr
#pragma unroll
  for (int d0 = 0; d0 < 8; ++d0) o[d0] = (f32x4){0.f, 0.f, 0.f, 0.f};

  const int qrow = wv * 16 + lr;
  const int shsrc = ((lr >> 2) << 4) + lr;  // lane with lq = lr>>2 for q=lr state

  for (int c = 0; c < 4; ++c) {
    const int buf = c & 1;
    // chunk c landed when <= 4 loads (chunk c+1) outstanding
    if (c < 3) asm volatile("s_waitcnt vmcnt(4)" ::: "memory");
    else       asm volatile("s_waitcnt vmcnt(0)" ::: "memory");
    __syncthreads();

    // ---- QK^T: 4 t-tiles x K=128 (Q frags resident in registers) ----
    f32x4 sc[4];
#pragma unroll
    for (int tt = 0; tt < 4; ++tt) {
      f32x4 a = (f32x4){0.f, 0.f, 0.f, 0.f};
#pragma unroll
      for (int kd = 0; kd < 4; ++kd) {
        bf16x8 kf = *(const bf16x8*)(sK[buf] + (size_t)(tt * 16 + lr) * 128 + (size_t)((kd * 4 + lq) ^ lr) * 8);
        a = __builtin_amdgcn_mfma_f32_16x16x32_bf16(qf[kd], kf, a, 0, 0, 0);
      }
      sc[tt] = a;
    }

    // ---- scale/clip/mask -> exp (max-free) -> local sum accumulate ----
#pragma unroll
    for (int tt = 0; tt < 4; ++tt) {
      const bool on = (mbits >> (c * 4 + tt)) & 1;
#pragma unroll
      for (int r = 0; r < 4; ++r) {
        float v = sc[tt][r] * scale;
        v = fminf(fmaxf(v, -50.f), 50.f);
        v = on ? v : -50.f;
        const float p = __expf(v);
        sc[tt][r] = p;
        ls[r] += p;
      }
    }

    // ---- P (C-layout) -> per-wave LDS (XOR swz, 16B slots) -> fragments ----
#pragma unroll
    for (int tt = 0; tt < 4; ++tt)
#pragma unroll
      for (int r = 0; r < 4; ++r) {
        const int q = lq * 4 + r;
        const int slot = (tt * 2 + (lr >> 3)) ^ ((q >> 1) & 7);
        sPw[(size_t)q * 64 + slot * 8 + (lr & 7)] = f2b(sc[tt][r]);
      }

    bf16x8 pf[2];
#pragma unroll
    for (int kt = 0; kt < 2; ++kt) {
      const int slot = (kt * 4 + lq) ^ ((lr >> 1) & 7);
      pf[kt] = *(const bf16x8*)(sPw + (size_t)lr * 64 + slot * 8);
    }

    // ---- PV transposed: o^T[d][q] += Vt_A . P^T_B ----
#pragma unroll
    for (int d0 = 0; d0 < 8; ++d0)
#pragma unroll
      for (int kt = 0; kt < 2; ++kt) {
        bf16x8 vf = *(const bf16x8*)(sVt[buf] + (size_t)(d0 * 16 + lr) * 64 + (size_t)((kt * 4 + lq) ^ (lr & 7)) * 8);
        o[d0] = __builtin_amdgcn_mfma_f32_16x16x32_bf16(vf, pf[kt], o[d0], 0, 0, 0);
      }
    if (c < 2) {
      __syncthreads();  // all waves done with buf before restaging it
      STAGE_KV(c + 2);
    }
  }
#undef STAGE_KV

  // ---- single sum reduce across lr, then 1/l redistributed to q=lr ----
#pragma unroll
  for (int d = 1; d < 16; d <<= 1)
#pragma unroll
    for (int r = 0; r < 4; ++r) ls[r] += __shfl_xor(ls[r], d);

  const float i0 = __shfl(1.0f / ls[0], shsrc), i1 = __shfl(1.0f / ls[1], shsrc);
  const float i2 = __shfl(1.0f / ls[2], shsrc), i3 = __shfl(1.0f / ls[3], shsrc);
  const int rsel = lr & 3;
  const float iq = rsel == 0 ? i0 : rsel == 1 ? i1 : rsel == 2 ? i2 : i3;

  // ctx[q][d]: lane holds q = s0blk + wv*16 + lr, d = d0*16 + lq*4 + r
  const size_t cbase = ((size_t)b * SS + s0blk + wv * 16 + lr) * HH + (size_t)h * HD;
#pragma unroll
  for (int d0 = 0; d0 < 8; ++d0) {
    uint2 w;
    w.x = (uint32_t)f2b(o[d0][0] * iq) | ((uint32_t)f2b(o[d0][1] * iq) << 16);
    w.y = (uint32_t)f2b(o[d0][2] * iq) | ((uint32_t)f2b(o[d0][3] * iq) << 16);
    *(uint2*)(ctx + cbase + d0 * 16 + lq * 4) = w;
  }
}

// -------- LayerNorm: bf16 delta in -> f32 out, rows of 2048 --------
__global__ __launch_bounds__(256)
void ln_kernel(const u16* __restrict__ in, float* __restrict__ out,
               const float* __restrict__ gamma, const float* __restrict__ beta) {
  const int row = blockIdx.x, tid = threadIdx.x;
  const u16* x = in + (size_t)row * 2048;
  const uint4 raw = *(const uint4*)(x + tid * 8);
  float xv[8];
  xv[0] = b2f(raw.x & 0xFFFFu); xv[1] = b2f(raw.x >> 16);
  xv[2] = b2f(raw.y & 0xFFFFu); xv[3] = b2f(raw.y >> 16);
  xv[4] = b2f(raw.z & 0xFFFFu); xv[5] = b2f(raw.z >> 16);
  xv[6] = b2f(raw.w & 0xFFFFu); xv[7] = b2f(raw.w >> 16);
  float s = 0.f, ss = 0.f;
#pragma unroll
  for (int i = 0; i < 8; ++i) { s += xv[i]; ss += xv[i] * xv[i]; }
#pragma unroll
  for (int d = 1; d < 64; d <<= 1) {
    s += __shfl_xor(s, d);
    ss += __shfl_xor(ss, d);
  }
  __shared__ float rbuf[8];
  const int w = tid >> 6;
  if ((tid & 63) == 0) { rbuf[w] = s; rbuf[4 + w] = ss; }
  __syncthreads();
  s = rbuf[0] + rbuf[1] + rbuf[2] + rbuf[3];
  ss = rbuf[4] + rbuf[5] + rbuf[6] + rbuf[7];
  const float mu = s * (1.0f / 2048.0f);
  const float var = ss * (1.0f / 2048.0f) - mu * mu;
  const float inv = rsqrtf(var + 1e-5f);
  const float4 g0 = *(const float4*)(gamma + tid * 8);
  const float4 g1 = *(const float4*)(gamma + tid * 8 + 4);
  const float4 b0 = *(const float4*)(beta + tid * 8);
  const float4 b1 = *(const float4*)(beta + tid * 8 + 4);
  float4 y0, y1;
  y0.x = (xv[0] - mu) * inv * g0.x + b0.x;
  y0.y = (xv[1] - mu) * inv * g0.y + b0.y;
  y0.z = (xv[2] - mu) * inv * g0.z + b0.z;
  y0.w = (xv[3] - mu) * inv * g0.w + b0.w;
  y1.x = (xv[4] - mu) * inv * g1.x + b1.x;
  y1.y = (xv[5] - mu) * inv * g1.y + b1.y;
  y1.z = (xv[6] - mu) * inv * g1.z + b1.z;
  y1.w = (xv[7] - mu) * inv * g1.w + b1.w;
  float* o = out + (size_t)row * 2048 + tid * 8;
  *(float4*)o = y0;
  *(float4*)(o + 4) = y1;
}

extern "C" void kernel_launch(void* const* d_in, const int* in_sizes, int n_in,
                              void* d_out, int out_size, void* d_ws, size_t ws_size,
                              hipStream_t stream) {
  (void)in_sizes; (void)n_in; (void)out_size; (void)ws_size;
  const float* hs = (const float*)d_in[0];
  const float* at = (const float*)d_in[1];
  const int* mask = (const int*)d_in[2];
  const float* Wq = (const float*)d_in[3];
  const float* bq = (const float*)d_in[4];
  const float* Wk = (const float*)d_in[5];
  const float* bk = (const float*)d_in[6];
  const float* Wv = (const float*)d_in[7];
  const float* bv = (const float*)d_in[8];
  const float* Wo = (const float*)d_in[9];
  const float* bo = (const float*)d_in[10];
  const float* lg = (const float*)d_in[11];
  const float* lb = (const float*)d_in[12];
  const float* rs = (const float*)d_in[13];

  // workspace layout (u16 elements); ctx aliases hs_bf (hs dead after Q-GEMM);
  // delta_bf aliases Q_bf (Q dead after attn)
  u16* hs_bf = (u16*)d_ws;              // 16,777,216
  u16* at_bf = hs_bf + 16777216;        //  2,097,152
  u16* Wq_bf = at_bf + 2097152;         //  4,194,304
  u16* Wk_bf = Wq_bf + 4194304;
  u16* Wv_bf = Wk_bf + 4194304;
  u16* Wo_bf = Wv_bf + 4194304;
  u16* Q_bf  = Wo_bf + 4194304;         // 16,777,216
  u16* K_bf  = Q_bf + 16777216;         //  2,097,152
  u16* Vt_bf = K_bf + 2097152;          //  2,097,152  => total 113,246,208 bytes
  u16* ctx_bf = hs_bf;                  // alias
  u16* delta_bf = Q_bf;                 // alias

  cast_all<<<34816, 256, 0, stream>>>(hs, at, Wq, Wk, Wv, Wo,
                                      hs_bf, at_bf, Wq_bf, Wk_bf, Wv_bf, Wo_bf);

  gemm8<0><<<dim3(8, 32), 512, 0, stream>>>(hs_bf, Wq_bf, bq, nullptr, Q_bf);
  gemm_kv<<<dim3(16, 8, 2), 256, 0, stream>>>(at_bf, Wk_bf, Wv_bf, bk, bv, K_bf, Vt_bf);

  attn_kernel<<<dim3(16, 16, 4), 512, 0, stream>>>(Q_bf, K_bf, Vt_bf, mask, ctx_bf);

  gemm8<3><<<dim3(8, 32), 512, 0, stream>>>(ctx_bf, Wo_bf, bo, rs, delta_bf);
  ln_kernel<<<8192, 256, 0, stream>>>(delta_bf, (float*)d_out, lg, lb);
}